// Round 3
// baseline (395.180 us; speedup 1.0000x reference)
//
#include <hip/hip_runtime.h>

typedef _Float16 half_t;
typedef __attribute__((ext_vector_type(8))) _Float16 half8;
typedef __attribute__((ext_vector_type(4))) _Float16 half4;
typedef __attribute__((ext_vector_type(2))) _Float16 half2_t;
typedef __attribute__((ext_vector_type(4))) float float4_t;

#define BN_EPS 1e-5f

constexpr int Nn = 64, Cc = 64, Tt = 300, Vv = 25, Ss = 3;
constexpr int TB   = 4;              // timesteps per block (300/4 = 75 exact)
constexpr int TWN  = TB * Vv;        // 100 = stage-2 N dimension
constexpr int NT   = 7;              // 7 n-tiles of 16 cover 112 >= 100
constexpr int XL_T = 32;             // v-stride (padded 25->32, pads ZERO = free K-pad)
constexpr int XL_C = TB * XL_T + 8;  // 136: frag reads land 2-way-bank = free
constexpr int XA_S = 72;             // c-stride of xa rows (144 B: 16B-aligned, 2-way banks)
constexpr int XA_R = NT * 16;        // 112 rows per s

// d_ws layout (written fresh by setup kernel every launch; ws re-poisoned each call)
constexpr int WS_AE = 0;                       // fp16 [s][w:32][v:32]   6144 B
constexpr int WS_WC = Ss * 32 * 32;            // fp16 [s][o:64][c:64]  24576 B
constexpr int WS_BN = WS_WC + Ss * Cc * Cc;    // as halfs offset; fp32 bnsc[64],bnsh[64]

__global__ void gcn_setup(const float* __restrict__ A,   const float* __restrict__ PA1,
                          const float* __restrict__ PA2, const float* __restrict__ Wc,
                          const float* __restrict__ bc,  const float* __restrict__ gamma,
                          const float* __restrict__ beta, const float* __restrict__ rmean,
                          const float* __restrict__ rvar, half_t* __restrict__ ws)
{
    const int tid = threadIdx.x;
    // AeT fp16 padded: ws[(s*32+w)*32 + v] = A*PA1+PA2 (0 outside 25x25)
    for (int e = tid; e < Ss * 32 * 32; e += 256) {
        int s = e >> 10, r = e & 1023, w = r >> 5, v = r & 31;
        float val = 0.f;
        if (v < Vv && w < Vv) {
            int ai = (s * Vv + v) * Vv + w;
            val = A[ai] * PA1[ai] + PA2[ai];
        }
        ws[WS_AE + e] = (half_t)val;
    }
    // Wc fp16 flat copy (layout (s,o,c) already A-frag friendly)
    for (int e = tid; e < Ss * Cc * Cc; e += 256)
        ws[WS_WC + e] = (half_t)Wc[e];
    // BN scale/shift with Sum_s bc folded in
    float* bn = (float*)(ws + WS_BN);
    if (tid < Cc) {
        float sc   = gamma[tid] * rsqrtf(rvar[tid] + BN_EPS);
        float bsum = bc[tid] + bc[Cc + tid] + bc[2 * Cc + tid];
        bn[tid]      = sc;
        bn[Cc + tid] = beta[tid] - rmean[tid] * sc + bsum * sc;
    }
}

__global__ __launch_bounds__(256, 2)
void gcn_fused(const float* __restrict__ x, const half_t* __restrict__ ws,
               float* __restrict__ out)
{
    __shared__ __align__(16) half_t Xl[Cc * XL_C];          // 17408 B
    __shared__ __align__(16) half_t xa3[Ss * XA_R * XA_S];  // 48384 B
    __shared__ float bnsc[Cc], bnsh[Cc];                    // 512 B  -> ~66 KB, 2 blocks/CU

    const int tid  = threadIdx.x;
    const int lane = tid & 63;
    const int wave = tid >> 6;      // 0..3
    const int col  = lane & 15;     // MFMA n/m lane index
    const int quad = lane >> 4;     // 0..3

    const int tb = blockIdx.x;      // 0..74
    const int n  = blockIdx.y;      // 0..63
    const int t0 = tb * TB;

    // ---- weights: 13 clean vector loads from ws (L2-resident) ----
    half8 ab[Ss][2], wf[Ss][2];
    #pragma unroll
    for (int s = 0; s < Ss; ++s) {
        #pragma unroll
        for (int wt = 0; wt < 2; ++wt)   // B[k=v][n=w]: n=col, k=quad*8+j
            ab[s][wt] = *(const half8*)&ws[WS_AE + (s * 32 + wt * 16 + col) * 32 + quad * 8];
        #pragma unroll
        for (int ks = 0; ks < 2; ++ks)   // A[m=o][k=c]: m=col, k=quad*8+j
            wf[s][ks] = *(const half8*)&ws[WS_WC + (s * Cc + wave * 16 + col) * Cc + ks * 32 + quad * 8];
    }
    {
        const float* bn = (const float*)(ws + WS_BN);
        if (tid < Cc)      bnsc[tid] = bn[tid];
        else if (tid < 2 * Cc) bnsh[tid - Cc] = bn[tid];
    }

    // ---- stage x slice into LDS: Xl[c][t][v], coalesced loads, half2 writes ----
    {
        const float* xb = x + (size_t)n * Cc * Tt * Vv + t0 * Vv;
        #pragma unroll
        for (int i = 0; i < 16; ++i) {
            int e = tid + i * 256;               // 4096 slots exact
            int c = e >> 6, r = e & 63, t = r >> 4, v0 = (r & 15) * 2;
            const float* p = xb + c * (Tt * Vv) + t * Vv + v0;
            float f0 = (v0     < Vv) ? p[0] : 0.f;
            float f1 = (v0 + 1 < Vv) ? p[1] : 0.f;
            half2_t hh = { (half_t)f0, (half_t)f1 };
            *(half2_t*)&Xl[c * XL_C + t * XL_T + v0] = hh;
        }
    }
    // ---- zero xa tail rows (tw 100..111, all 3 s) ----
    #pragma unroll
    for (int s = 0; s < Ss; ++s)
        for (int e = tid; e < (XA_R - TWN) * XA_S; e += 256)
            xa3[s * XA_R * XA_S + TWN * XA_S + e] = (half_t)0.f;

    __syncthreads();

    // ---- stage 1, all s batched: xa[s][c][(t,w)] = X · Ae[s]; wave owns t=wave ----
    {
        const int t = wave;
        #pragma unroll
        for (int ct = 0; ct < 4; ++ct) {
            // A-frag: m = c = ct*16+col, k = v = quad*8+j (v-pads zero)
            half8 af = *(const half8*)&Xl[(ct * 16 + col) * XL_C + t * XL_T + quad * 8];
            #pragma unroll
            for (int s = 0; s < Ss; ++s)
                #pragma unroll
                for (int wt = 0; wt < 2; ++wt) {
                    float4_t r = __builtin_amdgcn_mfma_f32_16x16x32_f16(
                        af, ab[s][wt], (float4_t){0.f, 0.f, 0.f, 0.f}, 0, 0, 0);
                    int w = wt * 16 + col;           // C/D: col = lane&15
                    if (w < Vv) {
                        half4 h;
                        #pragma unroll
                        for (int i = 0; i < 4; ++i) h[i] = (half_t)r[i];  // rows quad*4+i = c
                        *(half4*)&xa3[(s * XA_R + t * Vv + w) * XA_S + ct * 16 + quad * 4] = h;
                    }
                }
        }
    }
    __syncthreads();

    // ---- stage 2: y[o][(t,w)] = Sum_s Wc[s]·xa[s] — 42 MFMA uninterrupted ----
    const float4_t zero4 = {0.f, 0.f, 0.f, 0.f};
    float4_t yacc[NT];
    #pragma unroll
    for (int i = 0; i < NT; ++i) yacc[i] = zero4;

    #pragma unroll
    for (int s = 0; s < Ss; ++s)
        #pragma unroll
        for (int nt = 0; nt < NT; ++nt) {
            int tw = nt * 16 + col;                  // B-frag: n = tw
            #pragma unroll
            for (int ks = 0; ks < 2; ++ks) {
                half8 bf = *(const half8*)&xa3[(s * XA_R + tw) * XA_S + ks * 32 + quad * 8];
                yacc[nt] = __builtin_amdgcn_mfma_f32_16x16x32_f16(wf[s][ks], bf, yacc[nt], 0, 0, 0);
            }
        }

    // ---- epilogue: BN + residual (from Xl) + ReLU ----
    float* ob = out + (size_t)n * Cc * Tt * Vv + t0 * Vv;
    #pragma unroll
    for (int nt = 0; nt < NT; ++nt) {
        int tw = nt * 16 + col;
        if (tw < TWN) {
            int t = tw / Vv;            // magic mul
            int w = tw - t * Vv;
            #pragma unroll
            for (int i = 0; i < 4; ++i) {
                int o = wave * 16 + quad * 4 + i;
                float val = yacc[nt][i] * bnsc[o] + bnsh[o];
                val += (float)Xl[o * XL_C + t * XL_T + w];   // residual
                ob[o * Tt * Vv + tw] = fmaxf(val, 0.f);      // contiguous in tw
            }
        }
    }
}

extern "C" void kernel_launch(void* const* d_in, const int* in_sizes, int n_in,
                              void* d_out, int out_size, void* d_ws, size_t ws_size,
                              hipStream_t stream) {
    const float* x     = (const float*)d_in[0];
    const float* A     = (const float*)d_in[1];
    const float* PA1   = (const float*)d_in[2];
    const float* PA2   = (const float*)d_in[3];
    const float* Wc    = (const float*)d_in[4];
    const float* bc    = (const float*)d_in[5];
    const float* gamma = (const float*)d_in[6];
    const float* beta  = (const float*)d_in[7];
    const float* rmean = (const float*)d_in[8];
    const float* rvar  = (const float*)d_in[9];
    float* out = (float*)d_out;
    half_t* ws = (half_t*)d_ws;

    gcn_setup<<<1, 256, 0, stream>>>(A, PA1, PA2, Wc, bc, gamma, beta, rmean, rvar, ws);
    dim3 grid(Tt / TB, Nn);   // (75, 64)
    gcn_fused<<<grid, 256, 0, stream>>>(x, ws, out);
}

// Round 4
// 386.761 us; speedup vs baseline: 1.0218x; 1.0218x over previous
//
#include <hip/hip_runtime.h>

typedef _Float16 half_t;
typedef __attribute__((ext_vector_type(8))) _Float16 half8;
typedef __attribute__((ext_vector_type(4))) _Float16 half4;
typedef __attribute__((ext_vector_type(4))) float float4_t;

#define BN_EPS 1e-5f

constexpr int Nn = 64, Cc = 64, Tt = 300, Vv = 25, Ss = 3;
constexpr int SLABS = 16;            // grid = 64 n x 16 slabs = 1024 blocks (2 residency rounds)
constexpr int XL_TS = 32;            // Xl t-slot stride (v padded 25->32)
constexpr int XL_CS = 4 * XL_TS + 8; // 136 halfs per c row (+8 -> conflict-free frag reads)
constexpr int XA_RS = 72;            // xa row stride (144 B, 16B-aligned, balanced banks)

// ws layout (halfs): AE [s][w:32][v:32] zero-padded; WC [s][o:64][c:64] pre-scaled by bnsc;
// then fp32 bnsh[64] (byte offset 30720, 16B-aligned)
constexpr int WS_AE = 0;
constexpr int WS_WC = Ss * 32 * 32;
constexpr int WS_BN = WS_WC + Ss * Cc * Cc;

__global__ void gcn_setup(const float* __restrict__ A,   const float* __restrict__ PA1,
                          const float* __restrict__ PA2, const float* __restrict__ Wc,
                          const float* __restrict__ bc,  const float* __restrict__ gamma,
                          const float* __restrict__ beta, const float* __restrict__ rmean,
                          const float* __restrict__ rvar, half_t* __restrict__ ws)
{
    const int tid  = blockIdx.x * blockDim.x + threadIdx.x;
    const int nthr = gridDim.x * blockDim.x;
    for (int e = tid; e < Ss * 32 * 32; e += nthr) {      // AeT zero-padded to 32x32
        int s = e >> 10, r = e & 1023, w = r >> 5, v = r & 31;
        float val = 0.f;
        if (v < Vv && w < Vv) {
            int ai = (s * Vv + v) * Vv + w;
            val = A[ai] * PA1[ai] + PA2[ai];
        }
        ws[WS_AE + e] = (half_t)val;
    }
    for (int e = tid; e < Ss * Cc * Cc; e += nthr) {      // Wc * bnsc[o], layout (s,o,c)
        int o = (e >> 6) & 63;
        float sc = gamma[o] * rsqrtf(rvar[o] + BN_EPS);
        ws[WS_WC + e] = (half_t)(Wc[e] * sc);
    }
    float* bn = (float*)(ws + WS_BN);
    if (tid < Cc) {
        float sc   = gamma[tid] * rsqrtf(rvar[tid] + BN_EPS);
        float bsum = bc[tid] + bc[Cc + tid] + bc[2 * Cc + tid];
        bn[tid] = beta[tid] - rmean[tid] * sc + bsum * sc;
    }
}

__global__ __launch_bounds__(256, 2)
void gcn_fused(const float* __restrict__ x, const half_t* __restrict__ ws,
               float* __restrict__ out)
{
    __shared__ __align__(16) half_t Xl[Cc * XL_CS];        // 17408 B, per-wave t-slots
    __shared__ __align__(16) half_t xab[4 * 32 * XA_RS];   // 18432 B, wave-private xa

    const int tid  = threadIdx.x;
    const int lane = tid & 63;
    const int wave = tid >> 6;
    const int col  = lane & 15;
    const int quad = lane >> 4;

    const int n    = blockIdx.x & 63;
    const int slab = blockIdx.x >> 6;
    const int tbeg = (slab * Tt) / SLABS;
    const int tend = ((slab + 1) * Tt) / SLABS;            // slabs of 18/19 t

    // ---- all weights in registers (L2-resident clean vector loads) ----
    half8 ab[Ss][2];                  // Ae B-frags: B[k=v][n=w], rows k>=25 are zero
    half8 wf[Ss][2][4];               // Wc A-frags (bnsc-folded): A[m=o][k=c]
    #pragma unroll
    for (int s = 0; s < Ss; ++s) {
        #pragma unroll
        for (int wt = 0; wt < 2; ++wt)
            ab[s][wt] = *(const half8*)&ws[WS_AE + (s * 32 + wt * 16 + col) * 32 + quad * 8];
        #pragma unroll
        for (int ks = 0; ks < 2; ++ks)
            #pragma unroll
            for (int mt = 0; mt < 4; ++mt)
                wf[s][ks][mt] = *(const half8*)&ws[WS_WC + (s * Cc + mt * 16 + col) * Cc + ks * 32 + quad * 8];
    }
    float4_t bnsh4[4];                // shift for o = mt*16 + quad*4 + i
    {
        const float4_t* bnp = (const float4_t*)((const float*)(ws + WS_BN));
        #pragma unroll
        for (int mt = 0; mt < 4; ++mt) bnsh4[mt] = bnp[mt * 4 + quad];
    }

    // ---- one-time zero of my t-slot's v-pads (NaN safety; Ae zero-rows make values moot) ----
    #pragma unroll
    for (int v = Vv; v < 32; ++v)
        Xl[lane * XL_CS + wave * XL_TS + v] = (half_t)0.f;   // lane = c

    const float* xb = x   + (size_t)n * Cc * Tt * Vv;
    float*       ob = out + (size_t)n * Cc * Tt * Vv;
    half_t*      xw = &xab[wave * 32 * XA_RS];               // wave-private xa

    const int c0  = lane / 25;            // starting (c, v) for flat lane-blocked staging
    const int vd0 = lane - c0 * 25;
    const float4_t zero4 = {0.f, 0.f, 0.f, 0.f};

    for (int ch = 0; ch < 5; ++ch) {
        const int t = tbeg + ch * 4 + wave;
        if (t < tend) {
            // ---- stage 64 c-rows (1600 floats) of this t, lane-blocked flat -> MLP=25 ----
            float xv[25];
            {
                int vd = vd0, ga = c0 * (Tt * Vv) + t * Vv + vd0;
                #pragma unroll
                for (int i = 0; i < 25; ++i) {
                    xv[i] = xb[ga];
                    vd += 14; ga += 2 * (Tt * Vv) + 14;      // +64 elements = +2 rows +14
                    if (vd >= 25) { vd -= 25; ga += Tt * Vv - 25; }
                }
            }
            {
                int vd = vd0, la = c0 * XL_CS + wave * XL_TS + vd0;
                #pragma unroll
                for (int i = 0; i < 25; ++i) {
                    Xl[la] = (half_t)xv[i];
                    vd += 14; la += 2 * XL_CS + 14;
                    if (vd >= 25) { vd -= 25; la += XL_CS - 25; }
                }
            }
            asm volatile("s_waitcnt lgkmcnt(0)" ::: "memory");   // my wave's Xl writes done

            // ---- A-frags for this t: m = c = ct*16+col, k = v = quad*8+j ----
            half8 af[4];
            #pragma unroll
            for (int ct = 0; ct < 4; ++ct)
                af[ct] = *(const half8*)&Xl[(ct * 16 + col) * XL_CS + wave * XL_TS + quad * 8];

            float4_t yacc[4][2];
            #pragma unroll
            for (int mt = 0; mt < 4; ++mt) { yacc[mt][0] = zero4; yacc[mt][1] = zero4; }

            #pragma unroll
            for (int s = 0; s < Ss; ++s) {
                // stage 1: xa[w][c] = (X . Ae[s])^T rows; w>=25 rows compute to exact 0
                #pragma unroll
                for (int ct = 0; ct < 4; ++ct)
                    #pragma unroll
                    for (int wt = 0; wt < 2; ++wt) {
                        float4_t r = __builtin_amdgcn_mfma_f32_16x16x32_f16(af[ct], ab[s][wt], zero4, 0, 0, 0);
                        half4 h;
                        #pragma unroll
                        for (int i = 0; i < 4; ++i) h[i] = (half_t)r[i];   // rows = c = ct*16+quad*4+i
                        *(half4*)&xw[(wt * 16 + col) * XA_RS + ct * 16 + quad * 4] = h;
                    }
                asm volatile("s_waitcnt lgkmcnt(0)" ::: "memory");         // intra-wave RAW on xa

                // stage 2: y[o][w] += Wc'[s] . xa  (M=o=64, N=w, K=c=64)
                half8 bf[2][2];
                #pragma unroll
                for (int wt = 0; wt < 2; ++wt)
                    #pragma unroll
                    for (int ks = 0; ks < 2; ++ks)
                        bf[wt][ks] = *(const half8*)&xw[(wt * 16 + col) * XA_RS + ks * 32 + quad * 8];
                #pragma unroll
                for (int mt = 0; mt < 4; ++mt)
                    #pragma unroll
                    for (int wt = 0; wt < 2; ++wt)
                        #pragma unroll
                        for (int ks = 0; ks < 2; ++ks)
                            yacc[mt][wt] = __builtin_amdgcn_mfma_f32_16x16x32_f16(
                                wf[s][ks][mt], bf[wt][ks], yacc[mt][wt], 0, 0, 0);
            }

            // ---- epilogue: +bnsh, +residual (fp16 from Xl), ReLU, store ----
            #pragma unroll
            for (int mt = 0; mt < 4; ++mt)
                #pragma unroll
                for (int i = 0; i < 4; ++i) {
                    const int o = mt * 16 + quad * 4 + i;
                    float* orow = ob + o * (Tt * Vv) + t * Vv;
                    const half_t* xrow = &Xl[o * XL_CS + wave * XL_TS];
                    float v0 = yacc[mt][0][i] + bnsh4[mt][i] + (float)xrow[col];
                    orow[col] = fmaxf(v0, 0.f);
                    if (col < Vv - 16) {
                        float v1 = yacc[mt][1][i] + bnsh4[mt][i] + (float)xrow[16 + col];
                        orow[16 + col] = fmaxf(v1, 0.f);
                    }
                }
        }
    }
}

extern "C" void kernel_launch(void* const* d_in, const int* in_sizes, int n_in,
                              void* d_out, int out_size, void* d_ws, size_t ws_size,
                              hipStream_t stream) {
    const float* x     = (const float*)d_in[0];
    const float* A     = (const float*)d_in[1];
    const float* PA1   = (const float*)d_in[2];
    const float* PA2   = (const float*)d_in[3];
    const float* Wc    = (const float*)d_in[4];
    const float* bc    = (const float*)d_in[5];
    const float* gamma = (const float*)d_in[6];
    const float* beta  = (const float*)d_in[7];
    const float* rmean = (const float*)d_in[8];
    const float* rvar  = (const float*)d_in[9];
    float* out = (float*)d_out;
    half_t* ws = (half_t*)d_ws;

    gcn_setup<<<16, 256, 0, stream>>>(A, PA1, PA2, Wc, bc, gamma, beta, rmean, rvar, ws);
    gcn_fused<<<dim3(Nn * SLABS), 256, 0, stream>>>(x, ws, out);
}